// Round 6
// baseline (365.400 us; speedup 1.0000x reference)
//
#include <hip/hip_runtime.h>

typedef unsigned short u16;
typedef unsigned int u32;
typedef __attribute__((ext_vector_type(8))) short short8;
typedef __attribute__((ext_vector_type(4))) short short4v;
typedef __attribute__((ext_vector_type(4))) float f32x4;
typedef __attribute__((ext_vector_type(4))) float float4v;
typedef __attribute__((ext_vector_type(2))) u32 u32x2;
typedef __attribute__((ext_vector_type(4))) u32 u32x4;

#define S_LEN 8192
#define NHEAD 8
#define NBLK  128
#define SCALE_C 0.18033688011112042f   // log2(e)/sqrt(64), folded into stored q

__device__ __forceinline__ u16 f2b(float f) {
    union { float f; unsigned u; } v; v.f = f;
    unsigned r = v.u + 0x7FFFu + ((v.u >> 16) & 1u);
    return (u16)(r >> 16);
}
__device__ __forceinline__ float b2f(u16 b) {
    union { float f; unsigned u; } v; v.u = ((unsigned)b) << 16; return v.f;
}
__device__ __forceinline__ u32 cvt_pk_bf16(float lo, float hi) {
    u32 r;
    asm("v_cvt_pk_bf16_f32 %0, %1, %2" : "=v"(r) : "v"(lo), "v"(hi));
    return r;
}
// dual-result permlane swaps (verified round 4)
__device__ __forceinline__ void pl16swap(u32& a, u32& b) {
    u32x2 r = __builtin_amdgcn_permlane16_swap(a, b, false, false);
    a = r[0]; b = r[1];
}
__device__ __forceinline__ void pl32swap(u32& a, u32& b) {
    u32x2 r = __builtin_amdgcn_permlane32_swap(a, b, false, false);
    a = r[0]; b = r[1];
}
// XOR swizzle for [row][128B] LDS tiles (read side) — GEMM cores only
__device__ __forceinline__ int swz(int row, int colByte) {
    return row * 128 + (colByte ^ ((row & 7) << 4));
}
// async global->LDS, 16B per lane; LDS dest = wave-uniform base + lane*16
__device__ __forceinline__ void gload_lds(const void* g, void* l) {
    __builtin_amdgcn_global_load_lds(
        (const __attribute__((address_space(1))) void*)g,
        (__attribute__((address_space(3))) void*)l, 16, 0, 0);
}

// ---------------- converts ----------------
__global__ __launch_bounds__(256) void cvt_x_kernel(const float* __restrict__ x, u16* __restrict__ xb) {
    int idx = blockIdx.x * 256 + threadIdx.x;
    float4v v = *((const float4v*)x + idx);
    short4v o;
    #pragma unroll
    for (int r = 0; r < 4; ++r) o[r] = (short)f2b(v[r]);
    *((short4v*)xb + idx) = o;
}

// w: [512][C] fp32  ->  wt: [C][512] bf16
__global__ __launch_bounds__(256) void cvt_T_kernel(const float* __restrict__ w, u16* __restrict__ wt, int C) {
    int idx = blockIdx.x * 256 + threadIdx.x;   // over C*512
    int r = idx & 511, cc = idx >> 9;
    wt[idx] = f2b(w[(size_t)r * C + cc]);
}

// ---------------- GEMM core (m97 structure): async global->LDS staging, pre-swizzled source ----------------
__device__ __forceinline__ void gemm128_core(const u16* __restrict__ A,
                                             const u16* __restrict__ Bt,
                                             int m0, int n0, char* As, char* Bs,
                                             f32x4 acc[4][4]) {
    const int tid = threadIdx.x;
    const int lane = tid & 63, wid = tid >> 6;
    const int q16 = lane >> 4, l16 = lane & 15;
    const int wm = wid >> 1, wn = wid & 1;
    #pragma unroll 1
    for (int kt = 0; kt < 8; ++kt) {
        const int k0 = kt * 64;
        __syncthreads();   // previous compute done reading LDS
        #pragma unroll
        for (int p = 0; p < 4; ++p) {
            int c = tid + p * 256;
            int row = c >> 3, colp = (c & 7) ^ (row & 7);   // inverse-swizzled source col
            gload_lds(A  + (size_t)(m0 + row) * 512 + k0 + colp * 8, As + (size_t)(wid * 64 + p * 256) * 16);
            gload_lds(Bt + (size_t)(n0 + row) * 512 + k0 + colp * 8, Bs + (size_t)(wid * 64 + p * 256) * 16);
        }
        __syncthreads();   // drains vmcnt: tiles resident
        #pragma unroll
        for (int kk = 0; kk < 2; ++kk) {
            short8 a[4], b[4];
            #pragma unroll
            for (int t = 0; t < 4; ++t) {
                int arow = wm * 64 + t * 16 + l16;
                a[t] = *(const short8*)(As + swz(arow, kk * 64 + q16 * 16));
                int brow = wn * 64 + t * 16 + l16;
                b[t] = *(const short8*)(Bs + swz(brow, kk * 64 + q16 * 16));
            }
            #pragma unroll
            for (int mt = 0; mt < 4; ++mt)
                #pragma unroll
                for (int nt = 0; nt < 4; ++nt)
                    acc[mt][nt] = __builtin_amdgcn_mfma_f32_16x16x32_bf16(a[mt], b[nt], acc[mt][nt], 0, 0, 0);
        }
    }
}

// QKV GEMM epilogue:
//   q  -> [H][S][64] bf16, pre-scaled by SCALE_C
//   K  -> Kf[h][j][u] fragment-linear: u = (n0*2+c)*64 + q16*16 + l16, elem e;
//         element (key,d): n0=key>>4, l16=key&15, c=d>>5, q16=(d>>3)&3, e=d&7
//   V  -> Vf[h][j][u] fragment-linear: u = (dt*2+c)*64 + q16*16 + l16, elem e;
//         element (key,d): dt=d>>4, l16=d&15, c=key>>5, q16=(key>>3)&3, e=key&7
__global__ __launch_bounds__(256) void qkv_gemm(const u16* __restrict__ xb, const u16* __restrict__ wqkvT,
                                                const float* __restrict__ bqkv,
                                                u16* __restrict__ qb, u16* __restrict__ kf, u16* __restrict__ vf) {
    __shared__ char smem[32768];
    f32x4 acc[4][4];
    #pragma unroll
    for (int a = 0; a < 4; ++a)
        #pragma unroll
        for (int b = 0; b < 4; ++b) acc[a][b] = (f32x4){0.f, 0.f, 0.f, 0.f};
    const int m0 = blockIdx.x * 128, n0 = blockIdx.y * 128;
    gemm128_core(xb, wqkvT, m0, n0, smem, smem + 16384, acc);

    const int lane = threadIdx.x & 63, wid = threadIdx.x >> 6;
    const int q16 = lane >> 4, l16 = lane & 15;
    const int wm = wid >> 1, wn = wid & 1;
    #pragma unroll
    for (int mt = 0; mt < 4; ++mt) {
        #pragma unroll
        for (int nt = 0; nt < 4; ++nt) {
            int n = n0 + wn * 64 + nt * 16 + l16;
            float bias = bqkv[n];
            int t = n >> 9, h = (n >> 6) & 7, d = n & 63;
            int sb = m0 + wm * 64 + mt * 16 + q16 * 4;
            f32x4 v = acc[mt][nt];
            if (t == 0) {
                #pragma unroll
                for (int r = 0; r < 4; ++r)
                    qb[(size_t)(h * S_LEN + sb + r) * 64 + d] = f2b((v[r] + bias) * SCALE_C);
            } else if (t == 1) {
                int j = sb >> 6, key = sb & 63;
                int n0k = key >> 4, c = d >> 5, q16k = (d >> 3) & 3, e = d & 7;
                int ub = (n0k * 2 + c) * 64 + q16k * 16 + (key & 15);
                u16* base = kf + (size_t)h * 524288 + (size_t)j * 4096 + e;
                #pragma unroll
                for (int r = 0; r < 4; ++r)
                    base[(ub + r) * 8] = f2b(v[r] + bias);
            } else {
                int j = sb >> 6, key = sb & 63;
                int dt = d >> 4, c = key >> 5, q16v = (key >> 3) & 3, e0 = key & 7;
                int u = (dt * 2 + c) * 64 + q16v * 16 + (d & 15);
                short4v pk;
                #pragma unroll
                for (int r = 0; r < 4; ++r) pk[r] = (short)f2b(v[r] + bias);
                *(short4v*)(vf + (size_t)h * 524288 + (size_t)j * 4096 + u * 8 + e0) = pk;
            }
        }
    }
}

// out GEMM: fp32 out[s][n] = attn @ w_out + b_out
__global__ __launch_bounds__(256) void out_gemm(const u16* __restrict__ a0, const u16* __restrict__ wotT,
                                                const float* __restrict__ bout, float* __restrict__ out) {
    __shared__ char smem[32768];
    f32x4 acc[4][4];
    #pragma unroll
    for (int a = 0; a < 4; ++a)
        #pragma unroll
        for (int b = 0; b < 4; ++b) acc[a][b] = (f32x4){0.f, 0.f, 0.f, 0.f};
    const int m0 = blockIdx.x * 128, n0 = blockIdx.y * 128;
    gemm128_core(a0, wotT, m0, n0, smem, smem + 16384, acc);

    const int lane = threadIdx.x & 63, wid = threadIdx.x >> 6;
    const int q16 = lane >> 4, l16 = lane & 15;
    const int wm = wid >> 1, wn = wid & 1;
    #pragma unroll
    for (int mt = 0; mt < 4; ++mt) {
        #pragma unroll
        for (int nt = 0; nt < 4; ++nt) {
            int n = n0 + wn * 64 + nt * 16 + l16;
            float bias = bout[n];
            int sb = m0 + wm * 64 + mt * 16 + q16 * 4;
            #pragma unroll
            for (int r = 0; r < 4; ++r)
                out[(size_t)(sb + r) * 512 + n] = acc[mt][nt][r] + bias;
        }
    }
}

// ---------------- router (qb is pre-scaled by SCALE_C; compensate in the mean) ----------------
__global__ __launch_bounds__(256) void router_kernel(const u16* __restrict__ qb,
                                                     const float* __restrict__ w_r1, const float* __restrict__ b_r1,
                                                     const float* __restrict__ w_r2, const float* __restrict__ b_r2,
                                                     float* __restrict__ keepf) {
    const int nb = blockIdx.x, tid = threadIdx.x;
    __shared__ float rep[512];
    __shared__ float h1[128];
    for (int dim = tid; dim < 512; dim += 256) {
        int h = dim >> 6, d = dim & 63;
        const u16* p = qb + (size_t)(h * S_LEN + nb * 64) * 64 + d;
        float s = 0.f;
        #pragma unroll 4
        for (int t = 0; t < 64; ++t) s += b2f(p[t * 64]);
        rep[dim] = s * (0.015625f / SCALE_C);
    }
    __syncthreads();
    if (tid < 128) {
        float a = b_r1[tid];
        for (int k = 0; k < 512; ++k) a += rep[k] * w_r1[k * 128 + tid];
        h1[tid] = fmaxf(a, 0.f);
    }
    __syncthreads();
    if (tid < 64) {
        float v = h1[tid] * w_r2[tid] + h1[tid + 64] * w_r2[tid + 64];
        #pragma unroll
        for (int off = 32; off; off >>= 1) v += __shfl_down(v, off);
        if (tid == 0) {
            float z = v + b_r2[0];
            // sigmoid(z) >= 0.3  <=>  z >= ln(0.3/0.7)
            keepf[nb] = (z >= -0.84729786f) ? 1.0f : 0.0f;
        }
    }
}

// ---------------- block-sparse attention ----------------
// grid (64 q-tiles of 128, 8 heads, 4 j-quarters); 4 waves x 32q. K/V fragment-linear
// layouts: staging = linear gload_lds (no swizzle anywhere), ds_reads = const + lane*16.
// O contributions accumulated into fp32 attF via atomicAdd (zeroed per launch).
__global__ __launch_bounds__(256, 4) void attn_kernel(const u16* __restrict__ qb, const u16* __restrict__ kf,
                                                      const u16* __restrict__ vf, const float* __restrict__ keepf,
                                                      float* __restrict__ attF) {
    const int i = blockIdx.x, h = blockIdx.y, jh = blockIdx.z;
    const int j0 = jh * 32;
    const int tid = threadIdx.x, lane = tid & 63, wid = tid >> 6;
    const int q16 = lane >> 4, l16 = lane & 15;
    __shared__ char smem[32768];   // dbuf x (K 8K + V 8K), fragment-linear

    // Q fragments: 2 q-sub-tiles of 16 per wave
    short8 bq[2][2];
    #pragma unroll
    for (int qh = 0; qh < 2; ++qh) {
        const u16* qrow = qb + (size_t)(h * S_LEN + i * 128 + wid * 32 + qh * 16 + l16) * 64;
        bq[qh][0] = *(const short8*)(qrow + q16 * 8);
        bq[qh][1] = *(const short8*)(qrow + 32 + q16 * 8);
    }
    const int kq = i * 2 + (wid >> 1);          // this wave's 64-q block index
    const float keep_i = keepf[kq];
    const int qloc = (wid & 1) * 32 + l16;      // q within its 64-block, minus qh*16

    f32x4 o[2][4];
    #pragma unroll
    for (int qh = 0; qh < 2; ++qh)
        #pragma unroll
        for (int t = 0; t < 4; ++t) o[qh][t] = (f32x4){0.f, 0.f, 0.f, 0.f};

    const u16* kf_h = kf + (size_t)h * 524288;
    const u16* vf_h = vf + (size_t)h * 524288;
    const int lb = lane * 16;                    // ds_read lane offset (bytes)
    const int stoff = (wid * 128 + lane) * 8;    // staging source offset (u16)
    const int ldw = wid * 2048;                  // staging LDS base (bytes)

    // prologue: stage tile j0 into buf0
    {
        const size_t b = (size_t)j0 * 4096;
        gload_lds(kf_h + b + stoff,       smem + ldw);
        gload_lds(kf_h + b + stoff + 512, smem + ldw + 1024);
        gload_lds(vf_h + b + stoff,       smem + 8192 + ldw);
        gload_lds(vf_h + b + stoff + 512, smem + 8192 + ldw + 1024);
    }
    __syncthreads();

    for (int jj = 0; jj < 32; ++jj) {
        const int j = j0 + jj;
        char* Kc = smem + ((jj & 1) << 14);
        char* Vc = Kc + 8192;
        // prefetch tile j+1 into the other buffer (readers fenced last iter; writes
        // complete at this iter's end-of-loop barrier vmcnt drain)
        if (jj < 31) {
            char* Kn = smem + (((jj + 1) & 1) << 14);
            const size_t b = (size_t)(j + 1) * 4096;
            gload_lds(kf_h + b + stoff,       Kn + ldw);
            gload_lds(kf_h + b + stoff + 512, Kn + ldw + 1024);
            gload_lds(vf_h + b + stoff,       Kn + 8192 + ldw);
            gload_lds(vf_h + b + stoff + 512, Kn + 8192 + ldw + 1024);
        }
        const float gj = keep_i * keepf[j];

        // S^T = K . Q^T for both q-sub-tiles; fragment-linear A-operand reads
        f32x4 s4[2][4];
        __builtin_amdgcn_s_setprio(1);
        #pragma unroll
        for (int n0 = 0; n0 < 4; ++n0) {
            short8 ka0 = *(const short8*)(Kc + n0 * 2048 + lb);
            short8 ka1 = *(const short8*)(Kc + n0 * 2048 + 1024 + lb);
            #pragma unroll
            for (int qh = 0; qh < 2; ++qh) {
                f32x4 a = (f32x4){0.f, 0.f, 0.f, 0.f};
                a = __builtin_amdgcn_mfma_f32_16x16x32_bf16(ka0, bq[qh][0], a, 0, 0, 0);
                a = __builtin_amdgcn_mfma_f32_16x16x32_bf16(ka1, bq[qh][1], a, 0, 0, 0);
                s4[qh][n0] = a;
            }
        }
        __builtin_amdgcn_s_setprio(0);

        // softmax + P redistribute per q-sub-tile (verified permlane path)
        short8 pb[2][2];
        #pragma unroll
        for (int qh = 0; qh < 2; ++qh) {
            float pv[4][4];
            #pragma unroll
            for (int n0 = 0; n0 < 4; ++n0)
                #pragma unroll
                for (int r = 0; r < 4; ++r)
                    pv[n0][r] = __builtin_amdgcn_exp2f(s4[qh][n0][r]);
            if (j == kq) {   // strict upper triangle inside diagonal block (wave-uniform)
                const int qthis = qloc + qh * 16;
                #pragma unroll
                for (int n0 = 0; n0 < 4; ++n0)
                    #pragma unroll
                    for (int r = 0; r < 4; ++r)
                        if (n0 * 16 + q16 * 4 + r > qthis) pv[n0][r] = 0.f;
            }
            float sum = 0.f;
            #pragma unroll
            for (int n0 = 0; n0 < 4; ++n0)
                sum += (pv[n0][0] + pv[n0][1]) + (pv[n0][2] + pv[n0][3]);
            {   // butterfly over the 4 q16-groups
                u32 sa = __builtin_bit_cast(u32, sum), sb = sa;
                pl16swap(sa, sb);
                sum = __builtin_bit_cast(float, sa) + __builtin_bit_cast(float, sb);
                u32 sc = __builtin_bit_cast(u32, sum), sd = sc;
                pl32swap(sc, sd);
                sum = __builtin_bit_cast(float, sc) + __builtin_bit_cast(float, sd);
            }
            const float rinv = gj * __builtin_amdgcn_rcpf(sum);
            u32 dw[4][2];
            #pragma unroll
            for (int n0 = 0; n0 < 4; ++n0) {
                dw[n0][0] = cvt_pk_bf16(pv[n0][0] * rinv, pv[n0][1] * rinv);
                dw[n0][1] = cvt_pk_bf16(pv[n0][2] * rinv, pv[n0][3] * rinv);
            }
            #pragma unroll
            for (int kk = 0; kk < 2; ++kk) {
                u32 a0 = dw[2 * kk][0], b0 = dw[2 * kk + 1][0];
                pl32swap(a0, b0);
                pl16swap(a0, b0);
                u32 a1 = dw[2 * kk][1], b1 = dw[2 * kk + 1][1];
                pl32swap(a1, b1);
                pl16swap(a1, b1);
                u32x4 wv;
                wv[0] = a0; wv[1] = a1; wv[2] = b0; wv[3] = b1;
                pb[qh][kk] = __builtin_bit_cast(short8, wv);
            }
        }

        // O^T += V^T . P; fragment-linear A-operand reads
        __builtin_amdgcn_s_setprio(1);
        #pragma unroll
        for (int dt = 0; dt < 4; ++dt) {
            short8 va0 = *(const short8*)(Vc + dt * 2048 + lb);
            short8 va1 = *(const short8*)(Vc + dt * 2048 + 1024 + lb);
            #pragma unroll
            for (int qh = 0; qh < 2; ++qh) {
                o[qh][dt] = __builtin_amdgcn_mfma_f32_16x16x32_bf16(va0, pb[qh][0], o[qh][dt], 0, 0, 0);
                o[qh][dt] = __builtin_amdgcn_mfma_f32_16x16x32_bf16(va1, pb[qh][1], o[qh][dt], 0, 0, 0);
            }
        }
        __builtin_amdgcn_s_setprio(0);

        __syncthreads();   // fences LDS reads + drains prefetch vmcnt
    }

    // epilogue: atomic fp32 accumulation into attF[q][h*64 + d]
    #pragma unroll
    for (int qh = 0; qh < 2; ++qh) {
        float* obase = attF + (size_t)(i * 128 + wid * 32 + qh * 16 + l16) * 512 + h * 64 + q16 * 4;
        #pragma unroll
        for (int dt = 0; dt < 4; ++dt)
            #pragma unroll
            for (int r = 0; r < 4; ++r)
                atomicAdd(&obase[dt * 16 + r], o[qh][dt][r]);
    }
}

// ---------------- workspace layout (bytes); peak 43 MiB + 512 (same as proven) ----------------
static const size_t OFF_WQKVT = 0;                       // 1.5 MiB (pad 2)
static const size_t OFF_WOTT  = (size_t)2u << 20;        // 0.5 MiB (pad 1)
static const size_t OFF_QB    = (size_t)3u << 20;        // 8 MiB   (attnb alias after attn)
static const size_t OFF_KB    = (size_t)11u << 20;       // 8 MiB  Kf
static const size_t OFF_VT    = (size_t)19u << 20;       // 8 MiB  Vf
static const size_t OFF_ATTF  = (size_t)27u << 20;       // 16 MiB fp32 accum (27..43)
static const size_t OFF_XB    = (size_t)35u << 20;       // 8 MiB  (upper half of ATTF; xb dead before memset)
static const size_t OFF_KEEP  = (size_t)43u << 20;       // 512 B

extern "C" void kernel_launch(void* const* d_in, const int* in_sizes, int n_in,
                              void* d_out, int out_size, void* d_ws, size_t ws_size,
                              hipStream_t stream) {
    const float* x     = (const float*)d_in[0];
    const float* w_qkv = (const float*)d_in[1];
    const float* b_qkv = (const float*)d_in[2];
    const float* w_out = (const float*)d_in[3];
    const float* b_out = (const float*)d_in[4];
    const float* w_r1  = (const float*)d_in[5];
    const float* b_r1  = (const float*)d_in[6];
    const float* w_r2  = (const float*)d_in[7];
    const float* b_r2  = (const float*)d_in[8];
    float* out = (float*)d_out;
    char* ws = (char*)d_ws;
    u16* wqkvT  = (u16*)(ws + OFF_WQKVT);
    u16* wotT   = (u16*)(ws + OFF_WOTT);
    u16* qb     = (u16*)(ws + OFF_QB);
    u16* kf     = (u16*)(ws + OFF_KB);
    u16* vf     = (u16*)(ws + OFF_VT);
    float* attF = (float*)(ws + OFF_ATTF);
    u16* xb     = (u16*)(ws + OFF_XB);
    u16* attnb  = (u16*)(ws + OFF_QB);   // alias: qb dead after attn
    float* keepf = (float*)(ws + OFF_KEEP);

    cvt_x_kernel<<<4096, 256, 0, stream>>>(x, xb);
    cvt_T_kernel<<<3072, 256, 0, stream>>>(w_qkv, wqkvT, 1536);
    cvt_T_kernel<<<1024, 256, 0, stream>>>(w_out, wotT, 512);
    qkv_gemm<<<dim3(64, 12), 256, 0, stream>>>(xb, wqkvT, b_qkv, qb, kf, vf);
    router_kernel<<<128, 256, 0, stream>>>(qb, w_r1, b_r1, w_r2, b_r2, keepf);
    hipMemsetAsync(ws + OFF_ATTF, 0, (size_t)16u << 20, stream);   // zero attF (clobbers dead xb)
    attn_kernel<<<dim3(64, 8, 4), 256, 0, stream>>>(qb, kf, vf, keepf, attF);
    cvt_x_kernel<<<4096, 256, 0, stream>>>(attF, attnb);           // fp32 sum -> bf16
    out_gemm<<<dim3(64, 4), 256, 0, stream>>>(attnb, wotT, b_out, out);
}